// Round 8
// baseline (173.466 us; speedup 1.0000x reference)
//
#include <hip/hip_runtime.h>
#include <math.h>

// Problem constants
#define NN 2048      // nodes per modality
#define TWO_N 4096   // total nodes
#define BB 4         // batch
#define CC 64        // input feature dim
#define HD 128       // hidden dim
#define CANDCAP 32   // max candidates per row after margin filter

typedef unsigned short u16;
typedef _Float16 h16;
union H4 { ushort4 u; h16 h[4]; };
typedef _Float16 h16v8 __attribute__((ext_vector_type(8)));
typedef float f32v4 __attribute__((ext_vector_type(4)));

__device__ __forceinline__ u16 f2bf(float x) {   // RN-even f32 -> bf16
    unsigned u = __float_as_uint(x);
    u += 0x7FFFu + ((u >> 16) & 1u);
    return (u16)(u >> 16);
}

// ---------------------------------------------------------------------------
// 1) batch-mean + L2-normalize; also: DV/done zero, W1/W2 -> fp16 ([o][k]).
// ---------------------------------------------------------------------------
__global__ void k_mean_norm(const float* __restrict__ f1, const float* __restrict__ f2,
                            const float* __restrict__ W1, const float* __restrict__ W2,
                            float* __restrict__ g32T, double* __restrict__ gR64,
                            u16* __restrict__ xh,
                            u16* __restrict__ W1h, u16* __restrict__ W2h,
                            int* __restrict__ DV, int* __restrict__ done) {
    int n = blockIdx.x;           // node
    int m = blockIdx.y;           // modality
    int c = threadIdx.x;          // 64 threads = 1 wave
    if (m == 0 && n < 64) DV[n * 64 + c] = 0;   // covers 0..4095
    if (m == 0 && n == 64 && c == 0) *done = 0;
    if (m == 1) {
        if (n < 128) {            // W1h[o][k] fp16, elementwise
            int idx = n * 64 + c;
            ((h16*)W1h)[idx] = (h16)W1[idx];
        } else if (n < 384) {     // W2h[o][k] fp16
            int idx = (n - 128) * 64 + c;
            ((h16*)W2h)[idx] = (h16)W2[idx];
        }
    }
    const float* f = m ? f2 : f1;
    float xv[BB];
    double s = 0.0;
    for (int b = 0; b < BB; ++b) {
        float v = f[((size_t)(b * NN) + n) * CC + c];
        xv[b] = v; s += (double)v;
    }
    h16* xrow = (h16*)(xh + ((size_t)(m * NN + n)) * (BB * CC));
    for (int b = 0; b < BB; ++b) xrow[b * CC + c] = (h16)xv[b];
    double mean = s * 0.25;
    double sq = mean * mean;
    for (int d = 32; d >= 1; d >>= 1) sq += __shfl_xor(sq, d);
    double norm = sqrt(sq);
    if (norm < 1e-12) norm = 1e-12;
    double g = mean / norm;
    g32T[((size_t)m * CC + c) * NN + n] = (float)g;
    gR64[((size_t)m * NN + n) * CC + c] = g;
}

// ---------------------------------------------------------------------------
// 2) f32 sims GEMM, symmetric (upper-tri tiles), bf16 store + mirror via LDS.
// ---------------------------------------------------------------------------
__global__ void __launch_bounds__(256)
k_sims(const float* __restrict__ g32T, u16* __restrict__ simsbf) {
    __shared__ float As[64 * 64];   // 16 KB
    __shared__ float Bs[64 * 64];   // 16 KB
    int m  = blockIdx.y;
    int bi = blockIdx.x >> 5, bj = blockIdx.x & 31;
    if (bi > bj) return;            // uniform exit before barriers
    int i0 = bi * 64, j0 = bj * 64;
    const float* g = g32T + (size_t)m * CC * NN;
    int tid = threadIdx.x;
    #pragma unroll
    for (int q = 0; q < 16; ++q) {
        int idx = q * 256 + tid;
        int k = idx >> 6, r = idx & 63;
        As[k * 64 + r] = g[(size_t)k * NN + i0 + r];
        Bs[k * 64 + r] = g[(size_t)k * NN + j0 + r];
    }
    __syncthreads();
    int tr = tid >> 4, tc = tid & 15;
    float acc[4][4] = {{0.f}};
    #pragma unroll
    for (int k = 0; k < CC; ++k) {
        float4 a = *((const float4*)&As[k * 64 + (tr << 2)]);
        float4 b = *((const float4*)&Bs[k * 64 + (tc << 2)]);
        acc[0][0] += a.x * b.x; acc[0][1] += a.x * b.y; acc[0][2] += a.x * b.z; acc[0][3] += a.x * b.w;
        acc[1][0] += a.y * b.x; acc[1][1] += a.y * b.y; acc[1][2] += a.y * b.z; acc[1][3] += a.y * b.w;
        acc[2][0] += a.z * b.x; acc[2][1] += a.z * b.y; acc[2][2] += a.z * b.z; acc[2][3] += a.z * b.w;
        acc[3][0] += a.w * b.x; acc[3][1] += a.w * b.y; acc[3][2] += a.w * b.z; acc[3][3] += a.w * b.w;
    }
    __syncthreads();                // As free -> reuse as bf16 bounce [64][66]
    u16* Cs = (u16*)As;
    u16* srow = simsbf + (size_t)m * NN * NN;
    #pragma unroll
    for (int x = 0; x < 4; ++x) {
        ushort4 vd;
        vd.x = f2bf(acc[x][0]); vd.y = f2bf(acc[x][1]);
        vd.z = f2bf(acc[x][2]); vd.w = f2bf(acc[x][3]);
        *((ushort4*)&srow[(size_t)(i0 + (tr << 2) + x) * NN + j0 + (tc << 2)]) = vd;
        int cr = ((tr << 2) + x) * 66 + (tc << 2);
        Cs[cr + 0] = vd.x; Cs[cr + 1] = vd.y; Cs[cr + 2] = vd.z; Cs[cr + 3] = vd.w;
    }
    __syncthreads();
    #pragma unroll
    for (int q = 0; q < 4; ++q) {
        int idx = q * 256 + tid;
        int cc = idx >> 4, rr4 = (idx & 15) << 2;
        ushort4 vd;
        vd.x = Cs[(rr4 + 0) * 66 + cc];
        vd.y = Cs[(rr4 + 1) * 66 + cc];
        vd.z = Cs[(rr4 + 2) * 66 + cc];
        vd.w = Cs[(rr4 + 3) * 66 + cc];
        *((ushort4*)&srow[(size_t)(j0 + cc) * NN + i0 + rr4]) = vd;
    }
}

// ---------------------------------------------------------------------------
// 3) select (bf16, margin 6e-3) + f64-exact refine + FOLDED CSR scan
//    (last-block done-counter). Proven R7.
// ---------------------------------------------------------------------------
__global__ void __launch_bounds__(512)
k_selref(const u16* __restrict__ simsbf, const double* __restrict__ gR64,
         int* __restrict__ knn1, int* __restrict__ knn2, int* __restrict__ DV,
         int* __restrict__ done, int* __restrict__ offs,
         int* __restrict__ cursor, float* __restrict__ dvisf) {
    __shared__ int    candL[8][CANDCAP];
    __shared__ double dotsL[8][CANDCAP];
    __shared__ int    scanbuf[TWO_N];     // 16 KB (last block only)
    __shared__ int    wsum[8];
    __shared__ int    lastFlag;
    int wave = threadIdx.x >> 6, lane = threadIdx.x & 63;
    int row = blockIdx.x * 8 + wave;    // 0..4095
    int m = row >> 11, i = row & 2047;
    int K = m ? 13 : 19;
    const u16* s = simsbf + (size_t)m * NN * NN + (size_t)i * NN;
    float sv[32];
    #pragma unroll
    for (int q = 0; q < 4; ++q) {
        uint4 w = *((const uint4*)(s + q * 512 + (lane << 3)));
        sv[q*8+0] = __uint_as_float(w.x << 16);
        sv[q*8+1] = __uint_as_float(w.x & 0xFFFF0000u);
        sv[q*8+2] = __uint_as_float(w.y << 16);
        sv[q*8+3] = __uint_as_float(w.y & 0xFFFF0000u);
        sv[q*8+4] = __uint_as_float(w.z << 16);
        sv[q*8+5] = __uint_as_float(w.z & 0xFFFF0000u);
        sv[q*8+6] = __uint_as_float(w.w << 16);
        sv[q*8+7] = __uint_as_float(w.w & 0xFFFF0000u);
    }
    float lo = -1.01f, hi = 1.01f;
    for (int it = 0; it < 12; ++it) {
        float t = 0.5f * (lo + hi);
        int c = 0;
        #pragma unroll
        for (int r = 0; r < 32; ++r)
            c += __popcll(__ballot(sv[r] >= t));
        if (c >= K) lo = t; else hi = t;   // wave-uniform
    }
    float thr = lo - 6e-3f;
    unsigned long long ltmask = (lane == 0) ? 0ull : ((~0ull) >> (64 - lane));
    int base = 0;
    #pragma unroll
    for (int r = 0; r < 32; ++r) {
        int j = ((r >> 3) << 9) + (lane << 3) + (r & 7);
        bool p = sv[r] >= thr;
        unsigned long long mk = __ballot(p);
        int ofs = base + __popcll(mk & ltmask);
        if (p && ofs < CANDCAP) candL[wave][ofs] = j;
        base += __popcll(mk);
    }
    int cnt = (base < CANDCAP) ? base : CANDCAP;
    __syncthreads();
    const double* gm = gR64 + (size_t)m * NN * CC;
    double qc = gm[(size_t)i * CC + lane];
    int t4 = 0;
    for (; t4 + 3 < cnt; t4 += 4) {       // 4 independent reduce chains
        int j0c = candL[wave][t4 + 0], j1c = candL[wave][t4 + 1];
        int j2c = candL[wave][t4 + 2], j3c = candL[wave][t4 + 3];
        double p0 = qc * gm[(size_t)j0c * CC + lane];
        double p1 = qc * gm[(size_t)j1c * CC + lane];
        double p2 = qc * gm[(size_t)j2c * CC + lane];
        double p3 = qc * gm[(size_t)j3c * CC + lane];
        #pragma unroll
        for (int d = 32; d >= 1; d >>= 1) {
            p0 += __shfl_xor(p0, d); p1 += __shfl_xor(p1, d);
            p2 += __shfl_xor(p2, d); p3 += __shfl_xor(p3, d);
        }
        if (lane == 0) {
            dotsL[wave][t4 + 0] = p0; dotsL[wave][t4 + 1] = p1;
            dotsL[wave][t4 + 2] = p2; dotsL[wave][t4 + 3] = p3;
        }
    }
    for (; t4 < cnt; ++t4) {
        int j = candL[wave][t4];
        double p = qc * gm[(size_t)j * CC + lane];
        #pragma unroll
        for (int d = 32; d >= 1; d >>= 1) p += __shfl_xor(p, d);
        if (lane == 0) dotsL[wave][t4] = p;
    }
    __syncthreads();
    int* knn = m ? knn2 : knn1;
    if (lane < cnt) {
        double vt = dotsL[wave][lane]; int jt = candL[wave][lane];
        int rank = 0;
        for (int s2 = 0; s2 < cnt; ++s2) {
            double vs = dotsL[wave][s2]; int js = candL[wave][s2];
            if (vs > vt || (vs == vt && js < jt)) ++rank;
        }
        if (rank < K) {
            knn[(size_t)i * K + rank] = jt;
            int w = (rank < (m ? 5 : 7)) ? 2 : 1;
            atomicAdd(&DV[m ? NN + jt : jt], w);
        }
    }
    // ---- folded scan: last block to arrive does CSR offsets ----
    __syncthreads();
    if (threadIdx.x == 0) {
        int d = __hip_atomic_fetch_add(done, 1, __ATOMIC_ACQ_REL,
                                       __HIP_MEMORY_SCOPE_AGENT);
        lastFlag = (d == (int)gridDim.x - 1);
    }
    __syncthreads();
    if (lastFlag) {
        int t = threadIdx.x;
        #pragma unroll
        for (int q = 0; q < 8; ++q) scanbuf[q * 512 + t] = DV[q * 512 + t];
        __syncthreads();
        int loc[8]; int sum = 0;
        #pragma unroll
        for (int q = 0; q < 8; ++q) { loc[q] = scanbuf[t * 8 + q]; sum += loc[q]; }
        int x = sum;
        #pragma unroll
        for (int d = 1; d < 64; d <<= 1) {     // wave-inclusive scan
            int y = __shfl_up(x, d);
            if (lane >= d) x += y;
        }
        if (lane == 63) wsum[t >> 6] = x;
        __syncthreads();
        int wp = 0;
        for (int w = 0; w < (t >> 6); ++w) wp += wsum[w];
        int run = wp + x - sum;                 // exclusive prefix of this thread
        #pragma unroll
        for (int q = 0; q < 8; ++q) {
            int v = t * 8 + q;
            offs[v] = run; cursor[v] = run;
            dvisf[v] = (float)(1.0 / sqrt((double)(loc[q] + 1)));
            run += loc[q];
        }
        if (t == 511) offs[TWO_N] = run;
    }
}

// ---------------------------------------------------------------------------
// 4) MERGED: layer1 edge aggregation (blocks 0..4095) + CSR fill (4096..5119).
// ---------------------------------------------------------------------------
__global__ void k_edgeXfill(const u16* __restrict__ xh, const float* __restrict__ dvisf,
                            const int* __restrict__ knn1, const int* __restrict__ knn2,
                            int* __restrict__ cursor, int* __restrict__ entries,
                            u16* __restrict__ uh1) {
    int blk = blockIdx.x;
    int t = threadIdx.x;            // 64
    if (blk >= TWO_N) {             // fill: 1024 blocks x 64 = 65536 items
        int id = (blk - TWO_N) * 64 + t;
        const int M1 = NN * 19;
        if (id < M1) {
            int i = id / 19, tt = id % 19;
            int v = knn1[id];
            int p = atomicAdd(&cursor[v], 1); entries[p] = NN + i;
            if (tt < 7) { int p2 = atomicAdd(&cursor[v], 1); entries[p2] = i; }
        } else {
            int id2 = id - M1;      // < NN*13
            int i = id2 / 13, tt = id2 % 13;
            int v = NN + knn2[id2];
            int p = atomicAdd(&cursor[v], 1); entries[p] = 3 * NN + i;
            if (tt < 5) { int p2 = atomicAdd(&cursor[v], 1); entries[p2] = 2 * NN + i; }
        }
        return;
    }
    int off = t * 4;
    if (blk < NN) {                 // m1 pair: k6 (7) + k18 (19)
        int mv = 0; float wv = 0.f;
        if (t < 19) { mv = knn1[(size_t)blk * 19 + t]; wv = dvisf[mv]; }
        float a0=0,a1=0,a2=0,a3=0;
        #pragma unroll
        for (int q = 0; q < 7; ++q) {
            int mq = __shfl(mv, q); float wq = __shfl(wv, q);
            H4 hv; hv.u = *((const ushort4*)(xh + (size_t)mq * 256 + off));
            a0 += (float)hv.h[0]*wq; a1 += (float)hv.h[1]*wq;
            a2 += (float)hv.h[2]*wq; a3 += (float)hv.h[3]*wq;
        }
        { H4 ho; ho.h[0]=(h16)(a0*(1.f/49.f)); ho.h[1]=(h16)(a1*(1.f/49.f));
          ho.h[2]=(h16)(a2*(1.f/49.f)); ho.h[3]=(h16)(a3*(1.f/49.f));
          *((ushort4*)(uh1 + (size_t)blk * 256 + off)) = ho.u; }
        #pragma unroll
        for (int q = 7; q < 19; ++q) {
            int mq = __shfl(mv, q); float wq = __shfl(wv, q);
            H4 hv; hv.u = *((const ushort4*)(xh + (size_t)mq * 256 + off));
            a0 += (float)hv.h[0]*wq; a1 += (float)hv.h[1]*wq;
            a2 += (float)hv.h[2]*wq; a3 += (float)hv.h[3]*wq;
        }
        { H4 ho; ho.h[0]=(h16)(a0*(1.f/361.f)); ho.h[1]=(h16)(a1*(1.f/361.f));
          ho.h[2]=(h16)(a2*(1.f/361.f)); ho.h[3]=(h16)(a3*(1.f/361.f));
          *((ushort4*)(uh1 + (size_t)(NN + blk) * 256 + off)) = ho.u; }
    } else {                        // m2 pair: k4 (5) + k12 (13)
        int i = blk - NN;
        int mv = 0; float wv = 0.f;
        if (t < 13) { mv = knn2[(size_t)i * 13 + t]; wv = dvisf[NN + mv]; }
        float a0=0,a1=0,a2=0,a3=0;
        #pragma unroll
        for (int q = 0; q < 5; ++q) {
            int mq = __shfl(mv, q); float wq = __shfl(wv, q);
            H4 hv; hv.u = *((const ushort4*)(xh + (size_t)(NN + mq) * 256 + off));
            a0 += (float)hv.h[0]*wq; a1 += (float)hv.h[1]*wq;
            a2 += (float)hv.h[2]*wq; a3 += (float)hv.h[3]*wq;
        }
        { H4 ho; ho.h[0]=(h16)(a0*(1.f/25.f)); ho.h[1]=(h16)(a1*(1.f/25.f));
          ho.h[2]=(h16)(a2*(1.f/25.f)); ho.h[3]=(h16)(a3*(1.f/25.f));
          *((ushort4*)(uh1 + (size_t)(2 * NN + i) * 256 + off)) = ho.u; }
        #pragma unroll
        for (int q = 5; q < 13; ++q) {
            int mq = __shfl(mv, q); float wq = __shfl(wv, q);
            H4 hv; hv.u = *((const ushort4*)(xh + (size_t)(NN + mq) * 256 + off));
            a0 += (float)hv.h[0]*wq; a1 += (float)hv.h[1]*wq;
            a2 += (float)hv.h[2]*wq; a3 += (float)hv.h[3]*wq;
        }
        { H4 ho; ho.h[0]=(h16)(a0*(1.f/169.f)); ho.h[1]=(h16)(a1*(1.f/169.f));
          ho.h[2]=(h16)(a2*(1.f/169.f)); ho.h[3]=(h16)(a3*(1.f/169.f));
          *((ushort4*)(uh1 + (size_t)(3 * NN + i) * 256 + off)) = ho.u; }
    }
}

// ---------------------------------------------------------------------------
// 5) FUSED node1-gather + MFMA gemm1(relu) + gemm2 -> yh.
//    R4's fusion retried with 13 KB LDS (was 59 KB): gather phase now runs
//    at 5+ blocks/CU. Gather -> axT fp16 [32][72]; A-operand from LDS;
//    B-operand (W1h/W2h, [o][k] fp16) from global (L2-resident).
// ---------------------------------------------------------------------------
__global__ void __launch_bounds__(256)
k_nodeGemm12(const u16* __restrict__ uh1,
             const float* __restrict__ f1, const float* __restrict__ f2,
             const float* __restrict__ dvisf,
             const int* __restrict__ offs, const int* __restrict__ entries,
             const u16* __restrict__ W1h, const u16* __restrict__ W2h,
             u16* __restrict__ yh) {
    __shared__ h16 axT[32 * 72];     // 4.5 KB  [r'][k] fp16, pad 72
    __shared__ h16 zh[32 * 136];     // 8.5 KB
    int tid = threadIdx.x;
    int bid = blockIdx.x;            // 0..511
    int v0 = bid * 8, g0 = bid * 32;
    const float4* x1 = (const float4*)f1;
    const float4* x2 = (const float4*)f2;
    // ---- gather phase: 512 items = 8 nodes x 64 lanes ----
    #pragma unroll
    for (int it = 0; it < 2; ++it) {
        int item = it * 256 + tid;
        int vl = item >> 6, l6 = item & 63;
        int b = l6 >> 4, f4i = l6 & 15;
        int v = v0 + vl;
        int s = offs[v], e_end = offs[v + 1];
        float A0[4] = {0,0,0,0}, A1[4] = {0,0,0,0};
        float A2[4] = {0,0,0,0}, A3[4] = {0,0,0,0};
        int p = s;
        for (; p + 3 < e_end; p += 4) {
            H4 h0, h1, h2, h3;
            h0.u = *((const ushort4*)(uh1 + (size_t)entries[p+0] * 256 + l6 * 4));
            h1.u = *((const ushort4*)(uh1 + (size_t)entries[p+1] * 256 + l6 * 4));
            h2.u = *((const ushort4*)(uh1 + (size_t)entries[p+2] * 256 + l6 * 4));
            h3.u = *((const ushort4*)(uh1 + (size_t)entries[p+3] * 256 + l6 * 4));
            #pragma unroll
            for (int j = 0; j < 4; ++j) {
                A0[j] += (float)h0.h[j]; A1[j] += (float)h1.h[j];
                A2[j] += (float)h2.h[j]; A3[j] += (float)h3.h[j];
            }
        }
        for (; p < e_end; ++p) {
            H4 h0; h0.u = *((const ushort4*)(uh1 + (size_t)entries[p] * 256 + l6 * 4));
            #pragma unroll
            for (int j = 0; j < 4; ++j) A0[j] += (float)h0.h[j];
        }
        float r[4];
        #pragma unroll
        for (int j = 0; j < 4; ++j) r[j] = (A0[j] + A1[j]) + (A2[j] + A3[j]);
        int partner = (v < NN) ? v + NN : v - NN;
        float w0 = dvisf[v], w1 = dvisf[partner];
        float4 xv = (v < NN) ? x1[((size_t)(b * NN) + v) * 16 + f4i]
                             : x2[((size_t)(b * NN) + (v - NN)) * 16 + f4i];
        float4 xp = (partner < NN) ? x1[((size_t)(b * NN) + partner) * 16 + f4i]
                                   : x2[((size_t)(b * NN) + (partner - NN)) * 16 + f4i];
        r[0] += 0.25f * (xv.x * w0 + xp.x * w1);
        r[1] += 0.25f * (xv.y * w0 + xp.y * w1);
        r[2] += 0.25f * (xv.z * w0 + xp.z * w1);
        r[3] += 0.25f * (xv.w * w0 + xp.w * w1);
        int rloc = vl * 4 + b;
        #pragma unroll
        for (int j = 0; j < 4; ++j)
            axT[rloc * 72 + f4i * 4 + j] = (h16)(r[j] * w0);
    }
    __syncthreads();
    // ---- MFMA gemms ----
    int wid = tid >> 6, lane = tid & 63;
    int waveM = wid >> 1, waveN = wid & 1;
    int r0 = waveM * 16, c0 = waveN * 64;
    int lrow = lane & 15, lk8 = lane >> 4;      // A row / B col ; k-group
    const h16* w1p = (const h16*)W1h;
    const h16* w2p = (const h16*)W2h;
    f32v4 acc[4] = {{0.f,0.f,0.f,0.f},{0.f,0.f,0.f,0.f},
                    {0.f,0.f,0.f,0.f},{0.f,0.f,0.f,0.f}};
    #pragma unroll
    for (int ks = 0; ks < 2; ++ks) {            // gemm1: K=64
        int kb = ks * 32 + lk8 * 8;
        h16v8 a = *((const h16v8*)(axT + (size_t)(r0 + lrow) * 72 + kb));
        #pragma unroll
        for (int cb = 0; cb < 4; ++cb) {
            h16v8 b = *((const h16v8*)(w1p + (size_t)(c0 + cb * 16 + lrow) * CC + kb));
            acc[cb] = __builtin_amdgcn_mfma_f32_16x16x32_f16(a, b, acc[cb], 0, 0, 0);
        }
    }
    // relu -> zh fp16 (D: col = lane&15, row = (lane>>4)*4 + i)
    #pragma unroll
    for (int cb = 0; cb < 4; ++cb)
        #pragma unroll
        for (int i = 0; i < 4; ++i)
            zh[(r0 + lk8 * 4 + i) * 136 + c0 + cb * 16 + lrow] =
                (h16)fmaxf(acc[cb][i], 0.f);
    __syncthreads();
    f32v4 acc2[4] = {{0.f,0.f,0.f,0.f},{0.f,0.f,0.f,0.f},
                     {0.f,0.f,0.f,0.f},{0.f,0.f,0.f,0.f}};
    #pragma unroll
    for (int ks = 0; ks < 4; ++ks) {            // gemm2: K=128
        int kb = ks * 32 + lk8 * 8;
        h16v8 a = *((const h16v8*)(zh + (size_t)(r0 + lrow) * 136 + kb));
        #pragma unroll
        for (int cb = 0; cb < 4; ++cb) {
            h16v8 b = *((const h16v8*)(w2p + (size_t)(c0 + cb * 16 + lrow) * HD + kb));
            acc2[cb] = __builtin_amdgcn_mfma_f32_16x16x32_f16(a, b, acc2[cb], 0, 0, 0);
        }
    }
    h16* yp = (h16*)yh;
    #pragma unroll
    for (int cb = 0; cb < 4; ++cb)
        #pragma unroll
        for (int i = 0; i < 4; ++i)
            yp[(size_t)(g0 + r0 + lk8 * 4 + i) * HD + c0 + cb * 16 + lrow] =
                (h16)acc2[cb][i];
}

// ---------------------------------------------------------------------------
// 6) layer2 edge on fp16 y rows (1 KB). Grid 2NN x 128. (unchanged)
// ---------------------------------------------------------------------------
__global__ void k_edge2(const u16* __restrict__ yh, const float* __restrict__ dvisf,
                        const int* __restrict__ knn1, const int* __restrict__ knn2,
                        u16* __restrict__ uh2) {
    __shared__ int mem[19];
    __shared__ float wv[19];
    int blk = blockIdx.x;
    int t = threadIdx.x;            // 128
    int off = t * 4;
    if (blk < NN) {
        if (t < 19) { int v = knn1[(size_t)blk * 19 + t]; mem[t] = v; wv[t] = dvisf[v]; }
        __syncthreads();
        float a0=0,a1=0,a2=0,a3=0;
        #pragma unroll
        for (int q = 0; q < 7; ++q) {
            float w = wv[q];
            H4 hv; hv.u = *((const ushort4*)(yh + (size_t)mem[q] * 512 + off));
            a0 += (float)hv.h[0]*w; a1 += (float)hv.h[1]*w;
            a2 += (float)hv.h[2]*w; a3 += (float)hv.h[3]*w;
        }
        { H4 ho; ho.h[0]=(h16)(a0*(1.f/49.f)); ho.h[1]=(h16)(a1*(1.f/49.f));
          ho.h[2]=(h16)(a2*(1.f/49.f)); ho.h[3]=(h16)(a3*(1.f/49.f));
          *((ushort4*)(uh2 + (size_t)blk * 512 + off)) = ho.u; }
        #pragma unroll
        for (int q = 7; q < 19; ++q) {
            float w = wv[q];
            H4 hv; hv.u = *((const ushort4*)(yh + (size_t)mem[q] * 512 + off));
            a0 += (float)hv.h[0]*w; a1 += (float)hv.h[1]*w;
            a2 += (float)hv.h[2]*w; a3 += (float)hv.h[3]*w;
        }
        { H4 ho; ho.h[0]=(h16)(a0*(1.f/361.f)); ho.h[1]=(h16)(a1*(1.f/361.f));
          ho.h[2]=(h16)(a2*(1.f/361.f)); ho.h[3]=(h16)(a3*(1.f/361.f));
          *((ushort4*)(uh2 + (size_t)(NN + blk) * 512 + off)) = ho.u; }
    } else {
        int i = blk - NN;
        if (t < 13) { int v = NN + knn2[(size_t)i * 13 + t]; mem[t] = v; wv[t] = dvisf[v]; }
        __syncthreads();
        float a0=0,a1=0,a2=0,a3=0;
        #pragma unroll
        for (int q = 0; q < 5; ++q) {
            float w = wv[q];
            H4 hv; hv.u = *((const ushort4*)(yh + (size_t)mem[q] * 512 + off));
            a0 += (float)hv.h[0]*w; a1 += (float)hv.h[1]*w;
            a2 += (float)hv.h[2]*w; a3 += (float)hv.h[3]*w;
        }
        { H4 ho; ho.h[0]=(h16)(a0*(1.f/25.f)); ho.h[1]=(h16)(a1*(1.f/25.f));
          ho.h[2]=(h16)(a2*(1.f/25.f)); ho.h[3]=(h16)(a3*(1.f/25.f));
          *((ushort4*)(uh2 + (size_t)(2 * NN + i) * 512 + off)) = ho.u; }
        #pragma unroll
        for (int q = 5; q < 13; ++q) {
            float w = wv[q];
            H4 hv; hv.u = *((const ushort4*)(yh + (size_t)mem[q] * 512 + off));
            a0 += (float)hv.h[0]*w; a1 += (float)hv.h[1]*w;
            a2 += (float)hv.h[2]*w; a3 += (float)hv.h[3]*w;
        }
        { H4 ho; ho.h[0]=(h16)(a0*(1.f/169.f)); ho.h[1]=(h16)(a1*(1.f/169.f));
          ho.h[2]=(h16)(a2*(1.f/169.f)); ho.h[3]=(h16)(a3*(1.f/169.f));
          *((ushort4*)(uh2 + (size_t)(3 * NN + i) * 512 + off)) = ho.u; }
    }
}

// ---------------------------------------------------------------------------
// 7) layer2 node -> final output. (unchanged)
// ---------------------------------------------------------------------------
__global__ void k_node2(const u16* __restrict__ uh2, const u16* __restrict__ yh,
                        const float* __restrict__ dvisf,
                        const int* __restrict__ offs, const int* __restrict__ entries,
                        float* __restrict__ out) {
    int v = blockIdx.x;
    int t = threadIdx.x;            // 128
    int off = t * 4;
    int s = offs[v], e_end = offs[v + 1];
    float A0[4] = {0,0,0,0}, A1[4] = {0,0,0,0};
    float A2[4] = {0,0,0,0}, A3[4] = {0,0,0,0};
    int p = s;
    for (; p + 3 < e_end; p += 4) {
        H4 h0, h1, h2, h3;
        h0.u = *((const ushort4*)(uh2 + (size_t)entries[p+0] * 512 + off));
        h1.u = *((const ushort4*)(uh2 + (size_t)entries[p+1] * 512 + off));
        h2.u = *((const ushort4*)(uh2 + (size_t)entries[p+2] * 512 + off));
        h3.u = *((const ushort4*)(uh2 + (size_t)entries[p+3] * 512 + off));
        #pragma unroll
        for (int j = 0; j < 4; ++j) {
            A0[j] += (float)h0.h[j]; A1[j] += (float)h1.h[j];
            A2[j] += (float)h2.h[j]; A3[j] += (float)h3.h[j];
        }
    }
    for (; p < e_end; ++p) {
        H4 h0; h0.u = *((const ushort4*)(uh2 + (size_t)entries[p] * 512 + off));
        #pragma unroll
        for (int j = 0; j < 4; ++j) A0[j] += (float)h0.h[j];
    }
    float r[4];
    #pragma unroll
    for (int j = 0; j < 4; ++j) r[j] = (A0[j] + A1[j]) + (A2[j] + A3[j]);
    int partner = (v < NN) ? v + NN : v - NN;
    float w0 = dvisf[v], w1 = dvisf[partner];
    H4 yv, yp;
    yv.u = *((const ushort4*)(yh + (size_t)v * 512 + off));
    yp.u = *((const ushort4*)(yh + (size_t)partner * 512 + off));
    #pragma unroll
    for (int j = 0; j < 4; ++j) {
        r[j] += 0.25f * ((float)yv.h[j] * w0 + (float)yp.h[j] * w1);
        r[j] = fmaxf(r[j] * w0, 0.f);
    }
    int b = t >> 5, f4i = t & 31;
    size_t o4;
    if (v < NN) o4 = ((size_t)(b * NN + v)) * 32 + f4i;
    else        o4 = (size_t)BB * NN * 32 + ((size_t)(b * NN + (v - NN))) * 32 + f4i;
    ((float4*)out)[o4] = make_float4(r[0], r[1], r[2], r[3]);
}

// ---------------------------------------------------------------------------
extern "C" void kernel_launch(void* const* d_in, const int* in_sizes, int n_in,
                              void* d_out, int out_size, void* d_ws, size_t ws_size,
                              hipStream_t stream) {
    const float* f1 = (const float*)d_in[0];
    const float* f2 = (const float*)d_in[1];
    const float* W1 = (const float*)d_in[2];
    const float* W2 = (const float*)d_in[3];
    float* out = (float*)d_out;

    char* ws = (char*)d_ws;
    size_t off = 0;
    auto alloc = [&](size_t bytes) -> void* {
        void* p = ws + off;
        off = (off + bytes + 255) & ~(size_t)255;
        return p;
    };
    float*  g32T   = (float*)alloc((size_t)2 * CC * NN * 4);          // 1 MB
    double* gR64   = (double*)alloc((size_t)2 * NN * CC * 8);         // 2 MB
    u16*    simsbf = (u16*)alloc((size_t)2 * NN * NN * 2);            // 16 MB
    u16*    xh     = (u16*)alloc((size_t)TWO_N * BB * CC * 2);        // 2 MB
    u16*    uh1    = (u16*)alloc((size_t)4 * NN * BB * CC * 2);       // 4 MB
    u16*    yh     = (u16*)alloc((size_t)TWO_N * BB * HD * 2);        // 4 MB
    u16*    uh2    = (u16*)alloc((size_t)4 * NN * BB * HD * 2);       // 8 MB
    u16*    W1h    = (u16*)alloc((size_t)CC * HD * 2);
    u16*    W2h    = (u16*)alloc((size_t)HD * HD * 2);
    float*  dvisf  = (float*)alloc((size_t)TWO_N * 4);
    int*    knn1   = (int*)alloc((size_t)NN * 19 * 4);
    int*    knn2   = (int*)alloc((size_t)NN * 13 * 4);
    int*    DV     = (int*)alloc((size_t)TWO_N * 4);
    int*    done   = (int*)alloc(256);
    int*    offs   = (int*)alloc((size_t)(TWO_N + 1) * 4);
    int*    cursor = (int*)alloc((size_t)TWO_N * 4);
    int*    entries= (int*)alloc((size_t)(NN * 26 + NN * 18) * 4);

    // graph construction (scan folded into selref; fill folded into edgeX)
    k_mean_norm<<<dim3(NN, 2), 64, 0, stream>>>(f1, f2, W1, W2, g32T, gR64,
                                                xh, W1h, W2h, DV, done);
    k_sims<<<dim3(32 * 32, 2), 256, 0, stream>>>(g32T, simsbf);
    k_selref<<<TWO_N / 8, 512, 0, stream>>>(simsbf, gR64, knn1, knn2, DV,
                                            done, offs, cursor, dvisf);
    k_edgeXfill<<<TWO_N + 1024, 64, 0, stream>>>(xh, dvisf, knn1, knn2,
                                                 cursor, entries, uh1);

    // layer 1: fused gather + MFMA gemms (13 KB LDS -> high occupancy)
    k_nodeGemm12<<<(BB * TWO_N) / 32, 256, 0, stream>>>(uh1, f1, f2, dvisf, offs,
                                                        entries, W1h, W2h, yh);

    // layer 2
    k_edge2<<<2 * NN, 128, 0, stream>>>(yh, dvisf, knn1, knn2, uh2);
    k_node2<<<TWO_N, 128, 0, stream>>>(uh2, yh, dvisf, offs, entries, out);
}

// Round 9
// 170.854 us; speedup vs baseline: 1.0153x; 1.0153x over previous
//
#include <hip/hip_runtime.h>
#include <math.h>

// Problem constants
#define NN 2048      // nodes per modality
#define TWO_N 4096   // total nodes
#define BB 4         // batch
#define CC 64        // input feature dim
#define HD 128       // hidden dim
#define CANDCAP 32   // max candidates per row after margin filter

typedef unsigned short u16;
typedef _Float16 h16;
union H4 { ushort4 u; h16 h[4]; };
typedef _Float16 h16v8 __attribute__((ext_vector_type(8)));
typedef float f32v4 __attribute__((ext_vector_type(4)));

// Modality-partitioned XCD swizzle: blocks with (bid&7)<4 own modality-1
// nodes, (bid&7)>=4 own modality-2. Each XCD's gather working set drops to
// its modality's edge rows (L2-resident) instead of the union.
__device__ __forceinline__ int xcd_part(int bid) {
    return (bid & 7) * 512 + (bid >> 3);     // bijection on [0,4096)
}

__device__ __forceinline__ u16 f2bf(float x) {   // RN-even f32 -> bf16
    unsigned u = __float_as_uint(x);
    u += 0x7FFFu + ((u >> 16) & 1u);
    return (u16)(u >> 16);
}

// ---------------------------------------------------------------------------
// 1) batch-mean + L2-normalize; also: DV/done zero, W1/W2 -> fp16 ([o][k]).
// ---------------------------------------------------------------------------
__global__ void k_mean_norm(const float* __restrict__ f1, const float* __restrict__ f2,
                            const float* __restrict__ W1, const float* __restrict__ W2,
                            float* __restrict__ g32T, double* __restrict__ gR64,
                            u16* __restrict__ xh,
                            u16* __restrict__ W1h, u16* __restrict__ W2h,
                            int* __restrict__ DV, int* __restrict__ done) {
    int n = blockIdx.x;           // node
    int m = blockIdx.y;           // modality
    int c = threadIdx.x;          // 64 threads = 1 wave
    if (m == 0 && n < 64) DV[n * 64 + c] = 0;   // covers 0..4095
    if (m == 0 && n == 64 && c == 0) *done = 0;
    if (m == 1) {
        if (n < 128) {            // W1h[o][k] fp16, elementwise
            int idx = n * 64 + c;
            ((h16*)W1h)[idx] = (h16)W1[idx];
        } else if (n < 384) {     // W2h[o][k] fp16
            int idx = (n - 128) * 64 + c;
            ((h16*)W2h)[idx] = (h16)W2[idx];
        }
    }
    const float* f = m ? f2 : f1;
    float xv[BB];
    double s = 0.0;
    for (int b = 0; b < BB; ++b) {
        float v = f[((size_t)(b * NN) + n) * CC + c];
        xv[b] = v; s += (double)v;
    }
    h16* xrow = (h16*)(xh + ((size_t)(m * NN + n)) * (BB * CC));
    for (int b = 0; b < BB; ++b) xrow[b * CC + c] = (h16)xv[b];
    double mean = s * 0.25;
    double sq = mean * mean;
    for (int d = 32; d >= 1; d >>= 1) sq += __shfl_xor(sq, d);
    double norm = sqrt(sq);
    if (norm < 1e-12) norm = 1e-12;
    double g = mean / norm;
    g32T[((size_t)m * CC + c) * NN + n] = (float)g;
    gR64[((size_t)m * NN + n) * CC + c] = g;
}

// ---------------------------------------------------------------------------
// 2) f32 sims GEMM, symmetric (upper-tri tiles), bf16 store + mirror via LDS.
// ---------------------------------------------------------------------------
__global__ void __launch_bounds__(256)
k_sims(const float* __restrict__ g32T, u16* __restrict__ simsbf) {
    __shared__ float As[64 * 64];   // 16 KB
    __shared__ float Bs[64 * 64];   // 16 KB
    int m  = blockIdx.y;
    int bi = blockIdx.x >> 5, bj = blockIdx.x & 31;
    if (bi > bj) return;            // uniform exit before barriers
    int i0 = bi * 64, j0 = bj * 64;
    const float* g = g32T + (size_t)m * CC * NN;
    int tid = threadIdx.x;
    #pragma unroll
    for (int q = 0; q < 16; ++q) {
        int idx = q * 256 + tid;
        int k = idx >> 6, r = idx & 63;
        As[k * 64 + r] = g[(size_t)k * NN + i0 + r];
        Bs[k * 64 + r] = g[(size_t)k * NN + j0 + r];
    }
    __syncthreads();
    int tr = tid >> 4, tc = tid & 15;
    float acc[4][4] = {{0.f}};
    #pragma unroll
    for (int k = 0; k < CC; ++k) {
        float4 a = *((const float4*)&As[k * 64 + (tr << 2)]);
        float4 b = *((const float4*)&Bs[k * 64 + (tc << 2)]);
        acc[0][0] += a.x * b.x; acc[0][1] += a.x * b.y; acc[0][2] += a.x * b.z; acc[0][3] += a.x * b.w;
        acc[1][0] += a.y * b.x; acc[1][1] += a.y * b.y; acc[1][2] += a.y * b.z; acc[1][3] += a.y * b.w;
        acc[2][0] += a.z * b.x; acc[2][1] += a.z * b.y; acc[2][2] += a.z * b.z; acc[2][3] += a.z * b.w;
        acc[3][0] += a.w * b.x; acc[3][1] += a.w * b.y; acc[3][2] += a.w * b.z; acc[3][3] += a.w * b.w;
    }
    __syncthreads();                // As free -> reuse as bf16 bounce [64][66]
    u16* Cs = (u16*)As;
    u16* srow = simsbf + (size_t)m * NN * NN;
    #pragma unroll
    for (int x = 0; x < 4; ++x) {
        ushort4 vd;
        vd.x = f2bf(acc[x][0]); vd.y = f2bf(acc[x][1]);
        vd.z = f2bf(acc[x][2]); vd.w = f2bf(acc[x][3]);
        *((ushort4*)&srow[(size_t)(i0 + (tr << 2) + x) * NN + j0 + (tc << 2)]) = vd;
        int cr = ((tr << 2) + x) * 66 + (tc << 2);
        Cs[cr + 0] = vd.x; Cs[cr + 1] = vd.y; Cs[cr + 2] = vd.z; Cs[cr + 3] = vd.w;
    }
    __syncthreads();
    #pragma unroll
    for (int q = 0; q < 4; ++q) {
        int idx = q * 256 + tid;
        int cc = idx >> 4, rr4 = (idx & 15) << 2;
        ushort4 vd;
        vd.x = Cs[(rr4 + 0) * 66 + cc];
        vd.y = Cs[(rr4 + 1) * 66 + cc];
        vd.z = Cs[(rr4 + 2) * 66 + cc];
        vd.w = Cs[(rr4 + 3) * 66 + cc];
        *((ushort4*)&srow[(size_t)(j0 + cc) * NN + i0 + rr4]) = vd;
    }
}

// ---------------------------------------------------------------------------
// 3) select (bf16, margin 6e-3) + f64-exact refine + FOLDED CSR scan
//    (last-block done-counter). Proven R7.
// ---------------------------------------------------------------------------
__global__ void __launch_bounds__(512)
k_selref(const u16* __restrict__ simsbf, const double* __restrict__ gR64,
         int* __restrict__ knn1, int* __restrict__ knn2, int* __restrict__ DV,
         int* __restrict__ done, int* __restrict__ offs,
         int* __restrict__ cursor, float* __restrict__ dvisf) {
    __shared__ int    candL[8][CANDCAP];
    __shared__ double dotsL[8][CANDCAP];
    __shared__ int    scanbuf[TWO_N];     // 16 KB (last block only)
    __shared__ int    wsum[8];
    __shared__ int    lastFlag;
    int wave = threadIdx.x >> 6, lane = threadIdx.x & 63;
    int row = blockIdx.x * 8 + wave;    // 0..4095
    int m = row >> 11, i = row & 2047;
    int K = m ? 13 : 19;
    const u16* s = simsbf + (size_t)m * NN * NN + (size_t)i * NN;
    float sv[32];
    #pragma unroll
    for (int q = 0; q < 4; ++q) {
        uint4 w = *((const uint4*)(s + q * 512 + (lane << 3)));
        sv[q*8+0] = __uint_as_float(w.x << 16);
        sv[q*8+1] = __uint_as_float(w.x & 0xFFFF0000u);
        sv[q*8+2] = __uint_as_float(w.y << 16);
        sv[q*8+3] = __uint_as_float(w.y & 0xFFFF0000u);
        sv[q*8+4] = __uint_as_float(w.z << 16);
        sv[q*8+5] = __uint_as_float(w.z & 0xFFFF0000u);
        sv[q*8+6] = __uint_as_float(w.w << 16);
        sv[q*8+7] = __uint_as_float(w.w & 0xFFFF0000u);
    }
    float lo = -1.01f, hi = 1.01f;
    for (int it = 0; it < 12; ++it) {
        float t = 0.5f * (lo + hi);
        int c = 0;
        #pragma unroll
        for (int r = 0; r < 32; ++r)
            c += __popcll(__ballot(sv[r] >= t));
        if (c >= K) lo = t; else hi = t;   // wave-uniform
    }
    float thr = lo - 6e-3f;
    unsigned long long ltmask = (lane == 0) ? 0ull : ((~0ull) >> (64 - lane));
    int base = 0;
    #pragma unroll
    for (int r = 0; r < 32; ++r) {
        int j = ((r >> 3) << 9) + (lane << 3) + (r & 7);
        bool p = sv[r] >= thr;
        unsigned long long mk = __ballot(p);
        int ofs = base + __popcll(mk & ltmask);
        if (p && ofs < CANDCAP) candL[wave][ofs] = j;
        base += __popcll(mk);
    }
    int cnt = (base < CANDCAP) ? base : CANDCAP;
    __syncthreads();
    const double* gm = gR64 + (size_t)m * NN * CC;
    double qc = gm[(size_t)i * CC + lane];
    int t4 = 0;
    for (; t4 + 3 < cnt; t4 += 4) {       // 4 independent reduce chains
        int j0c = candL[wave][t4 + 0], j1c = candL[wave][t4 + 1];
        int j2c = candL[wave][t4 + 2], j3c = candL[wave][t4 + 3];
        double p0 = qc * gm[(size_t)j0c * CC + lane];
        double p1 = qc * gm[(size_t)j1c * CC + lane];
        double p2 = qc * gm[(size_t)j2c * CC + lane];
        double p3 = qc * gm[(size_t)j3c * CC + lane];
        #pragma unroll
        for (int d = 32; d >= 1; d >>= 1) {
            p0 += __shfl_xor(p0, d); p1 += __shfl_xor(p1, d);
            p2 += __shfl_xor(p2, d); p3 += __shfl_xor(p3, d);
        }
        if (lane == 0) {
            dotsL[wave][t4 + 0] = p0; dotsL[wave][t4 + 1] = p1;
            dotsL[wave][t4 + 2] = p2; dotsL[wave][t4 + 3] = p3;
        }
    }
    for (; t4 < cnt; ++t4) {
        int j = candL[wave][t4];
        double p = qc * gm[(size_t)j * CC + lane];
        #pragma unroll
        for (int d = 32; d >= 1; d >>= 1) p += __shfl_xor(p, d);
        if (lane == 0) dotsL[wave][t4] = p;
    }
    __syncthreads();
    int* knn = m ? knn2 : knn1;
    if (lane < cnt) {
        double vt = dotsL[wave][lane]; int jt = candL[wave][lane];
        int rank = 0;
        for (int s2 = 0; s2 < cnt; ++s2) {
            double vs = dotsL[wave][s2]; int js = candL[wave][s2];
            if (vs > vt || (vs == vt && js < jt)) ++rank;
        }
        if (rank < K) {
            knn[(size_t)i * K + rank] = jt;
            int w = (rank < (m ? 5 : 7)) ? 2 : 1;
            atomicAdd(&DV[m ? NN + jt : jt], w);
        }
    }
    // ---- folded scan: last block to arrive does CSR offsets ----
    __syncthreads();
    if (threadIdx.x == 0) {
        int d = __hip_atomic_fetch_add(done, 1, __ATOMIC_ACQ_REL,
                                       __HIP_MEMORY_SCOPE_AGENT);
        lastFlag = (d == (int)gridDim.x - 1);
    }
    __syncthreads();
    if (lastFlag) {
        int t = threadIdx.x;
        #pragma unroll
        for (int q = 0; q < 8; ++q) scanbuf[q * 512 + t] = DV[q * 512 + t];
        __syncthreads();
        int loc[8]; int sum = 0;
        #pragma unroll
        for (int q = 0; q < 8; ++q) { loc[q] = scanbuf[t * 8 + q]; sum += loc[q]; }
        int x = sum;
        #pragma unroll
        for (int d = 1; d < 64; d <<= 1) {     // wave-inclusive scan
            int y = __shfl_up(x, d);
            if (lane >= d) x += y;
        }
        if (lane == 63) wsum[t >> 6] = x;
        __syncthreads();
        int wp = 0;
        for (int w = 0; w < (t >> 6); ++w) wp += wsum[w];
        int run = wp + x - sum;                 // exclusive prefix of this thread
        #pragma unroll
        for (int q = 0; q < 8; ++q) {
            int v = t * 8 + q;
            offs[v] = run; cursor[v] = run;
            dvisf[v] = (float)(1.0 / sqrt((double)(loc[q] + 1)));
            run += loc[q];
        }
        if (t == 511) offs[TWO_N] = run;
    }
}

// ---------------------------------------------------------------------------
// 4) MERGED: layer1 edge aggregation (blocks 0..4095) + CSR fill (4096..5119).
// ---------------------------------------------------------------------------
__global__ void k_edgeXfill(const u16* __restrict__ xh, const float* __restrict__ dvisf,
                            const int* __restrict__ knn1, const int* __restrict__ knn2,
                            int* __restrict__ cursor, int* __restrict__ entries,
                            u16* __restrict__ uh1) {
    int blk = blockIdx.x;
    int t = threadIdx.x;            // 64
    if (blk >= TWO_N) {             // fill: 1024 blocks x 64 = 65536 items
        int id = (blk - TWO_N) * 64 + t;
        const int M1 = NN * 19;
        if (id < M1) {
            int i = id / 19, tt = id % 19;
            int v = knn1[id];
            int p = atomicAdd(&cursor[v], 1); entries[p] = NN + i;
            if (tt < 7) { int p2 = atomicAdd(&cursor[v], 1); entries[p2] = i; }
        } else {
            int id2 = id - M1;      // < NN*13
            int i = id2 / 13, tt = id2 % 13;
            int v = NN + knn2[id2];
            int p = atomicAdd(&cursor[v], 1); entries[p] = 3 * NN + i;
            if (tt < 5) { int p2 = atomicAdd(&cursor[v], 1); entries[p2] = 2 * NN + i; }
        }
        return;
    }
    blk = xcd_part(blk);            // modality-partitioned XCD locality
    int off = t * 4;
    if (blk < NN) {                 // m1 pair: k6 (7) + k18 (19)
        int mv = 0; float wv = 0.f;
        if (t < 19) { mv = knn1[(size_t)blk * 19 + t]; wv = dvisf[mv]; }
        float a0=0,a1=0,a2=0,a3=0;
        #pragma unroll
        for (int q = 0; q < 7; ++q) {
            int mq = __shfl(mv, q); float wq = __shfl(wv, q);
            H4 hv; hv.u = *((const ushort4*)(xh + (size_t)mq * 256 + off));
            a0 += (float)hv.h[0]*wq; a1 += (float)hv.h[1]*wq;
            a2 += (float)hv.h[2]*wq; a3 += (float)hv.h[3]*wq;
        }
        { H4 ho; ho.h[0]=(h16)(a0*(1.f/49.f)); ho.h[1]=(h16)(a1*(1.f/49.f));
          ho.h[2]=(h16)(a2*(1.f/49.f)); ho.h[3]=(h16)(a3*(1.f/49.f));
          *((ushort4*)(uh1 + (size_t)blk * 256 + off)) = ho.u; }
        #pragma unroll
        for (int q = 7; q < 19; ++q) {
            int mq = __shfl(mv, q); float wq = __shfl(wv, q);
            H4 hv; hv.u = *((const ushort4*)(xh + (size_t)mq * 256 + off));
            a0 += (float)hv.h[0]*wq; a1 += (float)hv.h[1]*wq;
            a2 += (float)hv.h[2]*wq; a3 += (float)hv.h[3]*wq;
        }
        { H4 ho; ho.h[0]=(h16)(a0*(1.f/361.f)); ho.h[1]=(h16)(a1*(1.f/361.f));
          ho.h[2]=(h16)(a2*(1.f/361.f)); ho.h[3]=(h16)(a3*(1.f/361.f));
          *((ushort4*)(uh1 + (size_t)(NN + blk) * 256 + off)) = ho.u; }
    } else {                        // m2 pair: k4 (5) + k12 (13)
        int i = blk - NN;
        int mv = 0; float wv = 0.f;
        if (t < 13) { mv = knn2[(size_t)i * 13 + t]; wv = dvisf[NN + mv]; }
        float a0=0,a1=0,a2=0,a3=0;
        #pragma unroll
        for (int q = 0; q < 5; ++q) {
            int mq = __shfl(mv, q); float wq = __shfl(wv, q);
            H4 hv; hv.u = *((const ushort4*)(xh + (size_t)(NN + mq) * 256 + off));
            a0 += (float)hv.h[0]*wq; a1 += (float)hv.h[1]*wq;
            a2 += (float)hv.h[2]*wq; a3 += (float)hv.h[3]*wq;
        }
        { H4 ho; ho.h[0]=(h16)(a0*(1.f/25.f)); ho.h[1]=(h16)(a1*(1.f/25.f));
          ho.h[2]=(h16)(a2*(1.f/25.f)); ho.h[3]=(h16)(a3*(1.f/25.f));
          *((ushort4*)(uh1 + (size_t)(2 * NN + i) * 256 + off)) = ho.u; }
        #pragma unroll
        for (int q = 5; q < 13; ++q) {
            int mq = __shfl(mv, q); float wq = __shfl(wv, q);
            H4 hv; hv.u = *((const ushort4*)(xh + (size_t)(NN + mq) * 256 + off));
            a0 += (float)hv.h[0]*wq; a1 += (float)hv.h[1]*wq;
            a2 += (float)hv.h[2]*wq; a3 += (float)hv.h[3]*wq;
        }
        { H4 ho; ho.h[0]=(h16)(a0*(1.f/169.f)); ho.h[1]=(h16)(a1*(1.f/169.f));
          ho.h[2]=(h16)(a2*(1.f/169.f)); ho.h[3]=(h16)(a3*(1.f/169.f));
          *((ushort4*)(uh1 + (size_t)(3 * NN + i) * 256 + off)) = ho.u; }
    }
}

// ---------------------------------------------------------------------------
// 5) layer1 node gather (R7 split restored; XCD modality partition added).
// ---------------------------------------------------------------------------
__global__ void k_node1(const u16* __restrict__ uh1,
                        const float* __restrict__ f1, const float* __restrict__ f2,
                        const float* __restrict__ dvisf,
                        const int* __restrict__ offs, const int* __restrict__ entries,
                        u16* __restrict__ aggxh) {
    int v = xcd_part(blockIdx.x);   // m1 nodes -> XCD 0-3 (uh1[0:2MB] L2-fit)
    int l6 = threadIdx.x;           // 64
    int b = l6 >> 4, f4i = l6 & 15;
    int s = offs[v], e_end = offs[v + 1];
    float A0[4] = {0,0,0,0}, A1[4] = {0,0,0,0};
    float A2[4] = {0,0,0,0}, A3[4] = {0,0,0,0};
    int p = s;
    for (; p + 3 < e_end; p += 4) {
        H4 h0, h1, h2, h3;
        h0.u = *((const ushort4*)(uh1 + (size_t)entries[p+0] * 256 + l6 * 4));
        h1.u = *((const ushort4*)(uh1 + (size_t)entries[p+1] * 256 + l6 * 4));
        h2.u = *((const ushort4*)(uh1 + (size_t)entries[p+2] * 256 + l6 * 4));
        h3.u = *((const ushort4*)(uh1 + (size_t)entries[p+3] * 256 + l6 * 4));
        #pragma unroll
        for (int j = 0; j < 4; ++j) {
            A0[j] += (float)h0.h[j]; A1[j] += (float)h1.h[j];
            A2[j] += (float)h2.h[j]; A3[j] += (float)h3.h[j];
        }
    }
    for (; p < e_end; ++p) {
        H4 h0; h0.u = *((const ushort4*)(uh1 + (size_t)entries[p] * 256 + l6 * 4));
        #pragma unroll
        for (int j = 0; j < 4; ++j) A0[j] += (float)h0.h[j];
    }
    float r[4];
    #pragma unroll
    for (int j = 0; j < 4; ++j) r[j] = (A0[j] + A1[j]) + (A2[j] + A3[j]);
    int partner = (v < NN) ? v + NN : v - NN;
    float w0 = dvisf[v], w1 = dvisf[partner];
    const float4* x1 = (const float4*)f1;
    const float4* x2 = (const float4*)f2;
    float4 xv = (v < NN) ? x1[((size_t)(b * NN) + v) * 16 + f4i]
                         : x2[((size_t)(b * NN) + (v - NN)) * 16 + f4i];
    float4 xp = (partner < NN) ? x1[((size_t)(b * NN) + partner) * 16 + f4i]
                               : x2[((size_t)(b * NN) + (partner - NN)) * 16 + f4i];
    r[0] += 0.25f * (xv.x * w0 + xp.x * w1);
    r[1] += 0.25f * (xv.y * w0 + xp.y * w1);
    r[2] += 0.25f * (xv.z * w0 + xp.z * w1);
    r[3] += 0.25f * (xv.w * w0 + xp.w * w1);
    H4 ho;
    #pragma unroll
    for (int j = 0; j < 4; ++j) ho.h[j] = (h16)(r[j] * w0);
    *((ushort4*)(aggxh + (size_t)v * 256 + l6 * 4)) = ho.u;
}

// ---------------------------------------------------------------------------
// 6) MFMA gemm12 (R7 split restored): z = relu(aggx @ W1^T), y = z @ W2^T.
// ---------------------------------------------------------------------------
__global__ void __launch_bounds__(256)
k_gemm12(const u16* __restrict__ aggxh,
         const u16* __restrict__ W1h, const u16* __restrict__ W2h,
         u16* __restrict__ yh) {
    __shared__ h16 zh[32 * 136];     // 8.5 KB
    int tid = threadIdx.x;
    int bid = blockIdx.x;            // 0..511
    int g0 = bid * 32;
    int wid = tid >> 6, lane = tid & 63;
    int waveM = wid >> 1, waveN = wid & 1;
    int r0 = waveM * 16, c0 = waveN * 64;
    int lrow = lane & 15, lk8 = lane >> 4;      // A row / B col ; k-group
    const h16* aggp = (const h16*)aggxh;
    const h16* w1p  = (const h16*)W1h;
    const h16* w2p  = (const h16*)W2h;
    // ---- gemm1: K=64, 2 ksteps ----
    f32v4 acc[4] = {{0.f,0.f,0.f,0.f},{0.f,0.f,0.f,0.f},
                    {0.f,0.f,0.f,0.f},{0.f,0.f,0.f,0.f}};
    #pragma unroll
    for (int ks = 0; ks < 2; ++ks) {
        int kb = ks * 32 + lk8 * 8;
        h16v8 a = *((const h16v8*)(aggp + (size_t)(g0 + r0 + lrow) * CC + kb));
        #pragma unroll
        for (int cb = 0; cb < 4; ++cb) {
            h16v8 b = *((const h16v8*)(w1p + (size_t)(c0 + cb * 16 + lrow) * CC + kb));
            acc[cb] = __builtin_amdgcn_mfma_f32_16x16x32_f16(a, b, acc[cb], 0, 0, 0);
        }
    }
    // relu -> zh fp16 (D: col = lane&15, row = (lane>>4)*4 + i)
    #pragma unroll
    for (int cb = 0; cb < 4; ++cb)
        #pragma unroll
        for (int i = 0; i < 4; ++i)
            zh[(r0 + lk8 * 4 + i) * 136 + c0 + cb * 16 + lrow] =
                (h16)fmaxf(acc[cb][i], 0.f);
    __syncthreads();
    // ---- gemm2: K=128, 4 ksteps, A from LDS ----
    f32v4 acc2[4] = {{0.f,0.f,0.f,0.f},{0.f,0.f,0.f,0.f},
                     {0.f,0.f,0.f,0.f},{0.f,0.f,0.f,0.f}};
    #pragma unroll
    for (int ks = 0; ks < 4; ++ks) {
        int kb = ks * 32 + lk8 * 8;
        h16v8 a = *((const h16v8*)(zh + (size_t)(r0 + lrow) * 136 + kb));
        #pragma unroll
        for (int cb = 0; cb < 4; ++cb) {
            h16v8 b = *((const h16v8*)(w2p + (size_t)(c0 + cb * 16 + lrow) * HD + kb));
            acc2[cb] = __builtin_amdgcn_mfma_f32_16x16x32_f16(a, b, acc2[cb], 0, 0, 0);
        }
    }
    h16* yp = (h16*)yh;
    #pragma unroll
    for (int cb = 0; cb < 4; ++cb)
        #pragma unroll
        for (int i = 0; i < 4; ++i)
            yp[(size_t)(g0 + r0 + lk8 * 4 + i) * HD + c0 + cb * 16 + lrow] =
                (h16)acc2[cb][i];
}

// ---------------------------------------------------------------------------
// 7) layer2 edge on fp16 y rows (1 KB). Grid 2NN x 128. XCD-partitioned:
//    m1 edges (gather yh m1 rows, 2 MB) -> XCD 0-3; m2 -> XCD 4-7.
// ---------------------------------------------------------------------------
__global__ void k_edge2(const u16* __restrict__ yh, const float* __restrict__ dvisf,
                        const int* __restrict__ knn1, const int* __restrict__ knn2,
                        u16* __restrict__ uh2) {
    __shared__ int mem[19];
    __shared__ float wv[19];
    int blk = xcd_part(blockIdx.x);
    int t = threadIdx.x;            // 128
    int off = t * 4;
    if (blk < NN) {
        if (t < 19) { int v = knn1[(size_t)blk * 19 + t]; mem[t] = v; wv[t] = dvisf[v]; }
        __syncthreads();
        float a0=0,a1=0,a2=0,a3=0;
        #pragma unroll
        for (int q = 0; q < 7; ++q) {
            float w = wv[q];
            H4 hv; hv.u = *((const ushort4*)(yh + (size_t)mem[q] * 512 + off));
            a0 += (float)hv.h[0]*w; a1 += (float)hv.h[1]*w;
            a2 += (float)hv.h[2]*w; a3 += (float)hv.h[3]*w;
        }
        { H4 ho; ho.h[0]=(h16)(a0*(1.f/49.f)); ho.h[1]=(h16)(a1*(1.f/49.f));
          ho.h[2]=(h16)(a2*(1.f/49.f)); ho.h[3]=(h16)(a3*(1.f/49.f));
          *((ushort4*)(uh2 + (size_t)blk * 512 + off)) = ho.u; }
        #pragma unroll
        for (int q = 7; q < 19; ++q) {
            float w = wv[q];
            H4 hv; hv.u = *((const ushort4*)(yh + (size_t)mem[q] * 512 + off));
            a0 += (float)hv.h[0]*w; a1 += (float)hv.h[1]*w;
            a2 += (float)hv.h[2]*w; a3 += (float)hv.h[3]*w;
        }
        { H4 ho; ho.h[0]=(h16)(a0*(1.f/361.f)); ho.h[1]=(h16)(a1*(1.f/361.f));
          ho.h[2]=(h16)(a2*(1.f/361.f)); ho.h[3]=(h16)(a3*(1.f/361.f));
          *((ushort4*)(uh2 + (size_t)(NN + blk) * 512 + off)) = ho.u; }
    } else {
        int i = blk - NN;
        if (t < 13) { int v = NN + knn2[(size_t)i * 13 + t]; mem[t] = v; wv[t] = dvisf[v]; }
        __syncthreads();
        float a0=0,a1=0,a2=0,a3=0;
        #pragma unroll
        for (int q = 0; q < 5; ++q) {
            float w = wv[q];
            H4 hv; hv.u = *((const ushort4*)(yh + (size_t)mem[q] * 512 + off));
            a0 += (float)hv.h[0]*w; a1 += (float)hv.h[1]*w;
            a2 += (float)hv.h[2]*w; a3 += (float)hv.h[3]*w;
        }
        { H4 ho; ho.h[0]=(h16)(a0*(1.f/25.f)); ho.h[1]=(h16)(a1*(1.f/25.f));
          ho.h[2]=(h16)(a2*(1.f/25.f)); ho.h[3]=(h16)(a3*(1.f/25.f));
          *((ushort4*)(uh2 + (size_t)(2 * NN + i) * 512 + off)) = ho.u; }
        #pragma unroll
        for (int q = 5; q < 13; ++q) {
            float w = wv[q];
            H4 hv; hv.u = *((const ushort4*)(yh + (size_t)mem[q] * 512 + off));
            a0 += (float)hv.h[0]*w; a1 += (float)hv.h[1]*w;
            a2 += (float)hv.h[2]*w; a3 += (float)hv.h[3]*w;
        }
        { H4 ho; ho.h[0]=(h16)(a0*(1.f/169.f)); ho.h[1]=(h16)(a1*(1.f/169.f));
          ho.h[2]=(h16)(a2*(1.f/169.f)); ho.h[3]=(h16)(a3*(1.f/169.f));
          *((ushort4*)(uh2 + (size_t)(3 * NN + i) * 512 + off)) = ho.u; }
    }
}

// ---------------------------------------------------------------------------
// 8) layer2 node -> final output. XCD-partitioned: m1 nodes gather uh2 rows
//    [0,2N) (4 MB, L2-fit) on XCD 0-3; m2 on 4-7.
// ---------------------------------------------------------------------------
__global__ void k_node2(const u16* __restrict__ uh2, const u16* __restrict__ yh,
                        const float* __restrict__ dvisf,
                        const int* __restrict__ offs, const int* __restrict__ entries,
                        float* __restrict__ out) {
    int v = xcd_part(blockIdx.x);
    int t = threadIdx.x;            // 128
    int off = t * 4;
    int s = offs[v], e_end = offs[v + 1];
    float A0[4] = {0,0,0,0}, A1[4] = {0,0,0,0};
    float A2[4] = {0,0,0,0}, A3[4] = {0,0,0,0};
    int p = s;
    for (; p + 3 < e_end; p += 4) {
        H4 h0, h1, h2, h3;
        h0.u = *((const ushort4*)(uh2 + (size_t)entries[p+0] * 512 + off));
        h1.u = *((const ushort4*)(uh2 + (size_t)entries[p+1] * 512 + off));
        h2.u = *((const ushort4*)(uh2 + (size_t)entries[p+2] * 512 + off));
        h3.u = *((const ushort4*)(uh2 + (size_t)entries[p+3] * 512 + off));
        #pragma unroll
        for (int j = 0; j < 4; ++j) {
            A0[j] += (float)h0.h[j]; A1[j] += (float)h1.h[j];
            A2[j] += (float)h2.h[j]; A3[j] += (float)h3.h[j];
        }
    }
    for (; p < e_end; ++p) {
        H4 h0; h0.u = *((const ushort4*)(uh2 + (size_t)entries[p] * 512 + off));
        #pragma unroll
        for (int j = 0; j < 4; ++j) A0[j] += (float)h0.h[j];
    }
    float r[4];
    #pragma unroll
    for (int j = 0; j < 4; ++j) r[j] = (A0[j] + A1[j]) + (A2[j] + A3[j]);
    int partner = (v < NN) ? v + NN : v - NN;
    float w0 = dvisf[v], w1 = dvisf[partner];
    H4 yv, yp;
    yv.u = *((const ushort4*)(yh + (size_t)v * 512 + off));
    yp.u = *((const ushort4*)(yh + (size_t)partner * 512 + off));
    #pragma unroll
    for (int j = 0; j < 4; ++j) {
        r[j] += 0.25f * ((float)yv.h[j] * w0 + (float)yp.h[j] * w1);
        r[j] = fmaxf(r[j] * w0, 0.f);
    }
    int b = t >> 5, f4i = t & 31;
    size_t o4;
    if (v < NN) o4 = ((size_t)(b * NN + v)) * 32 + f4i;
    else        o4 = (size_t)BB * NN * 32 + ((size_t)(b * NN + (v - NN))) * 32 + f4i;
    ((float4*)out)[o4] = make_float4(r[0], r[1], r[2], r[3]);
}

// ---------------------------------------------------------------------------
extern "C" void kernel_launch(void* const* d_in, const int* in_sizes, int n_in,
                              void* d_out, int out_size, void* d_ws, size_t ws_size,
                              hipStream_t stream) {
    const float* f1 = (const float*)d_in[0];
    const float* f2 = (const float*)d_in[1];
    const float* W1 = (const float*)d_in[2];
    const float* W2 = (const float*)d_in[3];
    float* out = (float*)d_out;

    char* ws = (char*)d_ws;
    size_t off = 0;
    auto alloc = [&](size_t bytes) -> void* {
        void* p = ws + off;
        off = (off + bytes + 255) & ~(size_t)255;
        return p;
    };
    float*  g32T   = (float*)alloc((size_t)2 * CC * NN * 4);          // 1 MB
    double* gR64   = (double*)alloc((size_t)2 * NN * CC * 8);         // 2 MB
    u16*    simsbf = (u16*)alloc((size_t)2 * NN * NN * 2);            // 16 MB
    u16*    xh     = (u16*)alloc((size_t)TWO_N * BB * CC * 2);        // 2 MB
    u16*    uh1    = (u16*)alloc((size_t)4 * NN * BB * CC * 2);       // 4 MB
    u16*    aggxh  = (u16*)alloc((size_t)TWO_N * BB * CC * 2);        // 2 MB
    u16*    yh     = (u16*)alloc((size_t)TWO_N * BB * HD * 2);        // 4 MB
    u16*    uh2    = (u16*)alloc((size_t)4 * NN * BB * HD * 2);       // 8 MB
    u16*    W1h    = (u16*)alloc((size_t)CC * HD * 2);
    u16*    W2h    = (u16*)alloc((size_t)HD * HD * 2);
    float*  dvisf  = (float*)alloc((size_t)TWO_N * 4);
    int*    knn1   = (int*)alloc((size_t)NN * 19 * 4);
    int*    knn2   = (int*)alloc((size_t)NN * 13 * 4);
    int*    DV     = (int*)alloc((size_t)TWO_N * 4);
    int*    done   = (int*)alloc(256);
    int*    offs   = (int*)alloc((size_t)(TWO_N + 1) * 4);
    int*    cursor = (int*)alloc((size_t)TWO_N * 4);
    int*    entries= (int*)alloc((size_t)(NN * 26 + NN * 18) * 4);

    // graph construction (scan folded into selref; fill folded into edgeX)
    k_mean_norm<<<dim3(NN, 2), 64, 0, stream>>>(f1, f2, W1, W2, g32T, gR64,
                                                xh, W1h, W2h, DV, done);
    k_sims<<<dim3(32 * 32, 2), 256, 0, stream>>>(g32T, simsbf);
    k_selref<<<TWO_N / 8, 512, 0, stream>>>(simsbf, gR64, knn1, knn2, DV,
                                            done, offs, cursor, dvisf);
    k_edgeXfill<<<TWO_N + 1024, 64, 0, stream>>>(xh, dvisf, knn1, knn2,
                                                 cursor, entries, uh1);

    // layer 1 (R7 split: gather at its own geometry, then MFMA gemms)
    k_node1<<<TWO_N, 64, 0, stream>>>(uh1, f1, f2, dvisf, offs, entries, aggxh);
    k_gemm12<<<(BB * TWO_N) / 32, 256, 0, stream>>>(aggxh, W1h, W2h, yh);

    // layer 2
    k_edge2<<<2 * NN, 128, 0, stream>>>(yh, dvisf, knn1, knn2, uh2);
    k_node2<<<TWO_N, 128, 0, stream>>>(uh2, yh, dvisf, offs, entries, out);
}